// Round 7
// baseline (324.926 us; speedup 1.0000x reference)
//
#include <hip/hip_runtime.h>
#include <hip/hip_bf16.h>
#include <math.h>

typedef unsigned short u16;
typedef float float4e __attribute__((ext_vector_type(4)));
typedef short short8 __attribute__((ext_vector_type(8)));
typedef unsigned short ushort8 __attribute__((ext_vector_type(8)));
typedef unsigned short u16x4 __attribute__((ext_vector_type(4)));

#define SEQ 2048
#define DIM 512
#define NB  4

__device__ __forceinline__ float bf2f(u16 h) {
    return __uint_as_float(((unsigned)h) << 16);
}
__device__ __forceinline__ u16 f2bf(float f) {
    __hip_bfloat16 h = __float2bfloat16(f);
    return *reinterpret_cast<u16*>(&h);
}
__device__ __forceinline__ float curv_of(float raw) {
    return -2.0f + 2.0f * (tanhf(raw) + 1.0f);   // bounds (-2,2)
}
// Hastings approximation, max abs err ~6.8e-5 rad — no divergent libm slow path
__device__ __forceinline__ float fast_acos(float x) {
    float ax = fabsf(x);
    float r = sqrtf(fmaxf(1.f - ax, 0.f)) *
              (1.5707288f + ax * (-0.2121144f + ax * (0.0742610f - 0.0187293f * ax)));
    return (x < 0.f) ? (3.14159265f - r) : r;
}
// async global->LDS, 16B per lane; lds base wave-uniform (lane lands at base+lane*16)
__device__ __forceinline__ void gl_lds16(const u16* g, u16* lds) {
    __builtin_amdgcn_global_load_lds(
        (const __attribute__((address_space(1))) unsigned int*)g,
        (__attribute__((address_space(3))) unsigned int*)lds, 16, 0, 0);
}

// ---------------- fused conversions + lsum zero + out zero (vectorized x4) ----------------
__global__ __launch_bounds__(256) void cvt_all_kernel(
    const float* __restrict__ x, const float* __restrict__ Wq,
    const float* __restrict__ Wk, const float* __restrict__ Wv,
    u16* __restrict__ x_bf, u16* __restrict__ Wcat, float* __restrict__ lsum,
    float* __restrict__ outz)
{
    const int n_x = NB * SEQ * DIM, n_w = DIM * DIM;
    const int n_out = NB * SEQ * DIM;
    int gid = blockIdx.x * 256 + threadIdx.x;
    if (gid < NB * SEQ) lsum[gid] = 0.f;
    if (gid < n_out / 4) ((float4*)outz)[gid] = (float4){0.f, 0.f, 0.f, 0.f};
    int i4 = gid * 4;
    if (i4 < n_x) {
        float4 v = *(const float4*)&x[i4];
        u16x4 h = {f2bf(v.x), f2bf(v.y), f2bf(v.z), f2bf(v.w)};
        *(u16x4*)&x_bf[i4] = h;
    } else if (i4 < n_x + 3 * n_w) {
        int j = i4 - n_x;
        const float* W = (j < n_w) ? Wq : (j < 2 * n_w ? Wk : Wv);
        int off = j % n_w;
        float4 v = *(const float4*)&W[off];
        u16x4 h = {f2bf(v.x), f2bf(v.y), f2bf(v.z), f2bf(v.w)};
        *(u16x4*)&Wcat[j] = h;
    }
}

// =====================================================================
// 128x128-tile GEMM, BK=64 (32 KB LDS, 32 MFMA per barrier-pair),
// global_load_lds 16B staging, mask-7 XOR swizzle (conflict-free b128 reads:
// granule = (kchunk ^ (R&7)) -> 16-lane phase covers all 8 granules 2x).
// MODE 0: QKV   C=bf16 [8192][1536], +bias; V columns also emit vT[b][d][s]
// MODE 1: scores C=attnH bf16, dist+exp epilogue + lsum atomics; causal skip
// MODE 2: PV    split-K x2, atomicAdd fp32 epilogue with 1/lsum
// =====================================================================
template<int MODE>
__global__ __launch_bounds__(256) void gemm128_kernel(
    const u16* __restrict__ A, int lda, long long sA,
    const u16* __restrict__ Bt, int ldb, long long sB,
    void* __restrict__ Cv, int ldc, long long sC,
    u16* __restrict__ vT,
    float* __restrict__ lsum,
    const float* __restrict__ bq, const float* __restrict__ bk, const float* __restrict__ bv,
    const float* __restrict__ qn2v, const float* __restrict__ kn2v,
    const float* __restrict__ curvp, const float* __restrict__ tempp)
{
    int bx = blockIdx.x, bm = blockIdx.y, b = blockIdx.z;
    int bn = (MODE == 2) ? (bx & 3) : bx;
    int kp = (MODE == 2) ? (bx >> 2) : 0;
    if (MODE == 1 && bn > bm) return;   // causal tile skip

    __shared__ __align__(16) u16 As[128 * 64];
    __shared__ __align__(16) u16 Bs[128 * 64];

    int t = threadIdx.x, wave = t >> 6, lane = t & 63;
    int wm = wave >> 1, wn = wave & 1;
    int lrow = lane & 15, quad = lane >> 4;
    int srow = lane >> 3, sc = lane & 7;   // staging: 8 rows x 8 chunks per wave-call

    const u16* Ab = A + (size_t)b * sA + (size_t)(bm * 128) * lda;
    const u16* Bb = Bt + (size_t)b * sB + (size_t)(bn * 128) * ldb;

    float4e acc[4][4];
#pragma unroll
    for (int i = 0; i < 4; i++)
#pragma unroll
        for (int j = 0; j < 4; j++) acc[i][j] = (float4e){0.f, 0.f, 0.f, 0.f};

    int ktBeg = (MODE == 2) ? kp : 0;
    int ktEnd = (MODE == 2) ? ((bm + 1) * 2) : 8;
    int ktStp = (MODE == 2) ? 2 : 1;

    for (int kt = ktBeg; kt < ktEnd; kt += ktStp) {
        int k0 = kt << 6;
        __syncthreads();
        // stage 128 rows x 64 cols (128 B/row = 8 chunks); chunk g of row r -> slot g^(r&7)
#pragma unroll
        for (int h = 0; h < 4; ++h) {
            int q = wave * 4 + h;           // 8-row group
            int row = q * 8 + srow;
            int c = sc ^ srow;              // row&7 == srow (groups 8-aligned)
            gl_lds16(Ab + (size_t)row * lda + k0 + c * 8, &As[q * 512]);
            gl_lds16(Bb + (size_t)row * ldb + k0 + c * 8, &Bs[q * 512]);
        }
        __syncthreads();

#pragma unroll
        for (int s = 0; s < 2; ++s) {
            short8 af[4], bfr[4];
#pragma unroll
            for (int im = 0; im < 4; im++) {
                int R = wm * 64 + im * 16 + lrow;
                af[im] = *(const short8*)&As[R * 64 + (((s * 4 + quad) ^ (R & 7)) * 8)];
            }
#pragma unroll
            for (int in = 0; in < 4; in++) {
                int R = wn * 64 + in * 16 + lrow;
                bfr[in] = *(const short8*)&Bs[R * 64 + (((s * 4 + quad) ^ (R & 7)) * 8)];
            }
#pragma unroll
            for (int im = 0; im < 4; im++)
#pragma unroll
                for (int in = 0; in < 4; in++)
                    acc[im][in] = __builtin_amdgcn_mfma_f32_16x16x32_bf16(af[im], bfr[in], acc[im][in], 0, 0, 0);
        }
    }

    // ---------------- epilogues ----------------
    if (MODE == 0) {
        u16* Cb = (u16*)Cv;
#pragma unroll
        for (int im = 0; im < 4; im++)
#pragma unroll
            for (int in = 0; in < 4; in++) {
                int gi0 = bm * 128 + wm * 64 + im * 16 + quad * 4;
                int gj = bn * 128 + wn * 64 + in * 16 + lrow;
                float bias = (gj < 512) ? bq[gj] : (gj < 1024 ? bk[gj - 512] : bv[gj - 1024]);
                u16x4 pack;
#pragma unroll
                for (int r = 0; r < 4; r++) {
                    u16 hv = f2bf(acc[im][in][r] + bias);
                    Cb[(size_t)(gi0 + r) * ldc + gj] = hv;
                    pack[r] = hv;
                }
                if (gj >= 1024) {   // also emit vT[b][d][s] (4 consecutive s -> 8B store)
                    int bb = gi0 >> 11, s = gi0 & 2047;
                    *(u16x4*)&vT[((size_t)bb * DIM + (gj - 1024)) * SEQ + s] = pack;
                }
            }
    } else if (MODE == 1) {
        float kv = curv_of(curvp[0]);
        float absk = fabsf(kv);
        float sk = sqrtf(fmaxf(absk, 1e-5f));
        float invsk = 1.0f / sk;
        float invT = 1.0f / (tempp[0] + 1e-8f);
        u16* Cb = (u16*)Cv + (size_t)b * sC;

        float psum[4][4];
#pragma unroll
        for (int im = 0; im < 4; im++)
#pragma unroll
            for (int r = 0; r < 4; r++) psum[im][r] = 0.f;

#pragma unroll
        for (int im = 0; im < 4; im++) {
#pragma unroll
            for (int r = 0; r < 4; r++) {
                int gi = bm * 128 + wm * 64 + im * 16 + quad * 4 + r;
                float qn = qn2v[b * SEQ + gi];
#pragma unroll
                for (int in = 0; in < 4; in++) {
                    int gj = bn * 128 + wn * 64 + in * 16 + lrow;
                    float kn = kn2v[b * SEQ + gj];
                    float dot = acc[im][in][r];
                    float diff2 = fmaxf(qn + kn - 2.f * dot, 0.f);
                    float dist;
                    if (absk < 0.01f) {
                        dist = sqrtf(diff2 + 1e-12f);
                    } else if (kv < 0.f) {
                        float denom = fmaxf((1.f - absk * qn) * (1.f - absk * kn), 1e-5f);
                        float arg = fmaxf(1.f + 2.f * absk * diff2 / denom, 1.f + 1e-7f);
                        dist = acoshf(arg) * invsk;
                    } else {
                        float c = fminf(fmaxf(absk * dot, -1.f + 1e-7f), 1.f - 1e-7f);
                        dist = fast_acos(c) * invsk;
                    }
                    float s = -dist * invT;
                    float e = (gj <= gi) ? __expf(s) : 0.f;   // scores<=0 -> no max shift
                    Cb[(size_t)gi * ldc + gj] = f2bf(e);
                    psum[im][r] += e;
                }
            }
        }
#pragma unroll
        for (int im = 0; im < 4; im++)
#pragma unroll
            for (int r = 0; r < 4; r++) {
                float v = psum[im][r];
                v += __shfl_xor(v, 1);
                v += __shfl_xor(v, 2);
                v += __shfl_xor(v, 4);
                v += __shfl_xor(v, 8);
                if (lrow == 0) {
                    int gi = bm * 128 + wm * 64 + im * 16 + quad * 4 + r;
                    atomicAdd(&lsum[b * SEQ + gi], v);
                }
            }
    } else {
        float* Cb = (float*)Cv + (size_t)b * sC;
#pragma unroll
        for (int im = 0; im < 4; im++)
#pragma unroll
            for (int r = 0; r < 4; r++) {
                int gi = bm * 128 + wm * 64 + im * 16 + quad * 4 + r;
                float invl = 1.0f / lsum[b * SEQ + gi];
#pragma unroll
                for (int in = 0; in < 4; in++) {
                    int gd = bn * 128 + wn * 64 + in * 16 + lrow;
                    atomicAdd(&Cb[(size_t)gi * ldc + gd], acc[im][in][r] * invl);
                }
            }
    }
}

// ---------------- projection: wave-per-row, 16B vector loads/stores ----------------
__global__ __launch_bounds__(256) void project_kernel(
    const u16* __restrict__ qkvh,
    u16* __restrict__ qm, u16* __restrict__ km,
    float* __restrict__ qn2, float* __restrict__ kn2,
    const float* __restrict__ curvp)
{
    int wave = threadIdx.x >> 6, lane = threadIdx.x & 63;
    int r = blockIdx.x * 4 + wave;
    float kv = curv_of(curvp[0]);
    float absk = fabsf(kv);
    float sk = sqrtf(fmaxf(absk, 1e-5f));

    const u16* qrow = qkvh + (size_t)r * 1536;
    ushort8 qh = *(const ushort8*)&qrow[lane * 8];
    ushort8 kh = *(const ushort8*)&qrow[512 + lane * 8];

    float qv[8], kw[8];
    float sq = 0.f, s2 = 0.f;
#pragma unroll
    for (int e = 0; e < 8; e++) {
        qv[e] = bf2f(qh[e]); sq += qv[e] * qv[e];
        kw[e] = bf2f(kh[e]); s2 += kw[e] * kw[e];
    }
#pragma unroll
    for (int off = 1; off < 64; off <<= 1) {
        sq += __shfl_xor(sq, off);
        s2 += __shfl_xor(s2, off);
    }

    float sclq, sclk;
    {
        float nq = sqrtf(sq + 1e-12f);
        float nk = sqrtf(s2 + 1e-12f);
        if (absk < 0.01f) { sclq = 1.f; sclk = 1.f; }
        else if (kv < 0.f) {
            float mx = (1.0f - 1e-3f) / sk;
            sclq = fminf(1.f, mx / nq);
            sclk = fminf(1.f, mx / nk);
        } else {
            sclq = 1.f / (nq * sk);
            sclk = 1.f / (nk * sk);
        }
    }
    if (lane == 0) {
        qn2[r] = sq * sclq * sclq;
        kn2[r] = s2 * sclk * sclk;
    }
    ushort8 qo, ko;
#pragma unroll
    for (int e = 0; e < 8; e++) {
        qo[e] = f2bf(qv[e] * sclq);
        ko[e] = f2bf(kw[e] * sclk);
    }
    *(ushort8*)&qm[(size_t)r * 512 + lane * 8] = qo;
    *(ushort8*)&km[(size_t)r * 512 + lane * 8] = ko;
}

// ---------------- normalize: attnH bf16 -> attnF fp32 (zero upper-tri) ----------------
__global__ __launch_bounds__(256) void norm_attn_kernel(
    const u16* __restrict__ attnH, const float* __restrict__ lsum,
    float* __restrict__ attnF)
{
    int i = blockIdx.x, b = blockIdx.y, t = threadIdx.x;
    float inv = 1.0f / lsum[b * SEQ + i];
    const u16* rowh = attnH + ((size_t)b * SEQ + i) * SEQ;
    float* row = attnF + ((size_t)b * SEQ + i) * SEQ;
    int L = i + 1;
    int j0 = t * 8;
    float4 lo, hi;
    if (j0 + 8 <= L) {
        ushort8 h = *(const ushort8*)&rowh[j0];
        lo.x = bf2f(h[0]) * inv; lo.y = bf2f(h[1]) * inv;
        lo.z = bf2f(h[2]) * inv; lo.w = bf2f(h[3]) * inv;
        hi.x = bf2f(h[4]) * inv; hi.y = bf2f(h[5]) * inv;
        hi.z = bf2f(h[6]) * inv; hi.w = bf2f(h[7]) * inv;
    } else {
        float v[8];
#pragma unroll
        for (int e = 0; e < 8; e++)
            v[e] = (j0 + e < L) ? bf2f(rowh[j0 + e]) * inv : 0.f;
        lo = (float4){v[0], v[1], v[2], v[3]};
        hi = (float4){v[4], v[5], v[6], v[7]};
    }
    *(float4*)&row[j0] = lo;
    *(float4*)&row[j0 + 4] = hi;
}

// ---------------- launch ----------------
extern "C" void kernel_launch(void* const* d_in, const int* in_sizes, int n_in,
                              void* d_out, int out_size, void* d_ws, size_t ws_size,
                              hipStream_t stream) {
    (void)in_sizes; (void)n_in; (void)out_size; (void)ws_size;

    const float* x    = (const float*)d_in[0];
    const float* Wq   = (const float*)d_in[1];
    const float* bq   = (const float*)d_in[2];
    const float* Wk   = (const float*)d_in[3];
    const float* bk   = (const float*)d_in[4];
    const float* Wv   = (const float*)d_in[5];
    const float* bv   = (const float*)d_in[6];
    const float* curv = (const float*)d_in[7];
    const float* temp = (const float*)d_in[8];

    float* out   = (float*)d_out;                       // [4][2048][512]
    float* attnF = out + (size_t)NB * SEQ * DIM;        // [4][2048][2048]

    char* ws = (char*)d_ws;
    // layout (bytes):
    //   0        x_bf    8,388,608   (dead after QKV)
    //   8388608  Wcat    1,572,864   (dead after QKV)
    //   9961472  qkvh   25,165,824   (dead after project)
    //   35127296 qm      8,388,608
    //   43515904 km      8,388,608
    //   51904512 vT      8,388,608   (written by QKV epilogue)
    //   60293120 qn2        32,768
    //   60325888 kn2        32,768
    //   60358656 lsum       32,768
    // attnH (33,554,432) aliases [0, 33554432) — x_bf/Wcat/qkvh all dead by then.
    u16*   x_bf  = (u16*)(ws + 0);
    u16*   Wcat  = (u16*)(ws + 8388608);
    u16*   qkvh  = (u16*)(ws + 9961472);
    u16*   qm    = (u16*)(ws + 35127296);
    u16*   km    = (u16*)(ws + 43515904);
    u16*   vT    = (u16*)(ws + 51904512);
    float* qn2   = (float*)(ws + 60293120);
    float* kn2   = (float*)(ws + 60325888);
    float* lsum  = (float*)(ws + 60358656);
    u16*   attnH = (u16*)(ws + 0);

    // K0: conversions + lsum zero + out zero
    {
        int n_tot = (NB * SEQ * DIM + 3 * DIM * DIM) / 4;
        cvt_all_kernel<<<(n_tot + 255) / 256, 256, 0, stream>>>(x, Wq, Wk, Wv, x_bf, Wcat, lsum, out);
    }

    // K1: QKV GEMM (M=8192, N=1536, K=512) + bias + fused V-transpose
    gemm128_kernel<0><<<dim3(1536 / 128, 8192 / 128, 1), 256, 0, stream>>>(
        x_bf, 512, 0, Wcat, 512, 0, (void*)qkvh, 1536, 0,
        vT, nullptr, bq, bk, bv, nullptr, nullptr, nullptr, nullptr);

    // K2: projection
    project_kernel<<<NB * SEQ / 4, 256, 0, stream>>>(qkvh, qm, km, qn2, kn2, curv);

    // K3: scores + dist + exp (unnormalized bf16) + row sums
    gemm128_kernel<1><<<dim3(SEQ / 128, SEQ / 128, NB), 256, 0, stream>>>(
        qm, 512, (long long)SEQ * DIM, km, 512, (long long)SEQ * DIM,
        (void*)attnH, SEQ, (long long)SEQ * SEQ,
        nullptr, lsum, nullptr, nullptr, nullptr, qn2, kn2, curv, temp);

    // K4: PV split-K x2 (128-tile), atomicAdd with 1/l scaling
    gemm128_kernel<2><<<dim3(2 * DIM / 128, SEQ / 128, NB), 256, 0, stream>>>(
        attnH, SEQ, (long long)SEQ * SEQ, vT, SEQ, (long long)DIM * SEQ,
        (void*)out, DIM, (long long)SEQ * DIM,
        nullptr, lsum, nullptr, nullptr, nullptr, nullptr, nullptr, nullptr, nullptr);

    // K5: attention fp32 output from bf16 + 1/l
    norm_attn_kernel<<<dim3(SEQ, NB), 256, 0, stream>>>(attnH, lsum, attnF);
}

// Round 8
// 244.799 us; speedup vs baseline: 1.3273x; 1.3273x over previous
//
#include <hip/hip_runtime.h>
#include <hip/hip_bf16.h>
#include <math.h>

typedef unsigned short u16;
typedef float float4e __attribute__((ext_vector_type(4)));
typedef short short8 __attribute__((ext_vector_type(8)));
typedef unsigned short ushort8 __attribute__((ext_vector_type(8)));
typedef unsigned short u16x4 __attribute__((ext_vector_type(4)));

#define SEQ 2048
#define DIM 512
#define NB  4

__device__ __forceinline__ float bf2f(u16 h) {
    return __uint_as_float(((unsigned)h) << 16);
}
__device__ __forceinline__ u16 f2bf(float f) {
    __hip_bfloat16 h = __float2bfloat16(f);
    return *reinterpret_cast<u16*>(&h);
}
__device__ __forceinline__ float curv_of(float raw) {
    return -2.0f + 2.0f * (tanhf(raw) + 1.0f);   // bounds (-2,2)
}
// Hastings approximation, max abs err ~6.8e-5 rad — no divergent libm slow path
__device__ __forceinline__ float fast_acos(float x) {
    float ax = fabsf(x);
    float r = sqrtf(fmaxf(1.f - ax, 0.f)) *
              (1.5707288f + ax * (-0.2121144f + ax * (0.0742610f - 0.0187293f * ax)));
    return (x < 0.f) ? (3.14159265f - r) : r;
}
// async global->LDS, 16B per lane; lds base wave-uniform (lane lands at base+lane*16)
__device__ __forceinline__ void gl_lds16(const u16* g, u16* lds) {
    __builtin_amdgcn_global_load_lds(
        (const __attribute__((address_space(1))) unsigned int*)g,
        (__attribute__((address_space(3))) unsigned int*)lds, 16, 0, 0);
}

// =====================================================================
// QKV GEMM, 64x64 tile, BK=64, fp32 inputs staged inline (load float4 ->
// cvt bf16 -> swizzled ds_write_b128). C=bf16 qkvh [8192][1536] +bias;
// V columns (gj>=1024) also emit vT[b][d][s].
// =====================================================================
__global__ __launch_bounds__(256, 4) void qkv_kernel(
    const float* __restrict__ xf,
    const float* __restrict__ Wq, const float* __restrict__ Wk, const float* __restrict__ Wv,
    const float* __restrict__ bq, const float* __restrict__ bk, const float* __restrict__ bv,
    u16* __restrict__ C, u16* __restrict__ vT)
{
    int bn = blockIdx.x, bm = blockIdx.y;

    __shared__ __align__(16) u16 As[64 * 64];
    __shared__ __align__(16) u16 Bs[64 * 64];

    int t = threadIdx.x, wave = t >> 6, lane = t & 63;
    int wr = wave >> 1, wc = wave & 1;
    int lrow = lane & 15, quad = lane >> 4;
    int srow = lane >> 3, sc = lane & 7;

    const float* Af = xf + (size_t)(bm * 64) * 512;
    const float* Wsel = (bn < 8) ? Wq : (bn < 16 ? Wk : Wv);
    const float* Bf = Wsel + (size_t)((bn & 7) * 64) * 512;

    float4e acc[2][2];
#pragma unroll
    for (int i = 0; i < 2; i++)
#pragma unroll
        for (int j = 0; j < 2; j++) acc[i][j] = (float4e){0.f, 0.f, 0.f, 0.f};

    for (int kt = 0; kt < 8; ++kt) {
        int k0 = kt << 6;
        __syncthreads();
        // stage 64x64 fp32 -> bf16; chunk (8 elems) c of row r -> slot sc = c^(r&7)
#pragma unroll
        for (int h = 0; h < 2; ++h) {
            int q = wave * 2 + h;
            int row = q * 8 + srow;
            int c = sc ^ srow;              // row&7 == srow
            const float* ga = Af + (size_t)row * 512 + k0 + c * 8;
            float4 a0 = *(const float4*)ga, a1 = *(const float4*)(ga + 4);
            const float* gb = Bf + (size_t)row * 512 + k0 + c * 8;
            float4 b0 = *(const float4*)gb, b1 = *(const float4*)(gb + 4);
            ushort8 ha, hb;
            ha[0] = f2bf(a0.x); ha[1] = f2bf(a0.y); ha[2] = f2bf(a0.z); ha[3] = f2bf(a0.w);
            ha[4] = f2bf(a1.x); ha[5] = f2bf(a1.y); ha[6] = f2bf(a1.z); ha[7] = f2bf(a1.w);
            hb[0] = f2bf(b0.x); hb[1] = f2bf(b0.y); hb[2] = f2bf(b0.z); hb[3] = f2bf(b0.w);
            hb[4] = f2bf(b1.x); hb[5] = f2bf(b1.y); hb[6] = f2bf(b1.z); hb[7] = f2bf(b1.w);
            *(ushort8*)&As[(size_t)row * 64 + sc * 8] = ha;
            *(ushort8*)&Bs[(size_t)row * 64 + sc * 8] = hb;
        }
        __syncthreads();
#pragma unroll
        for (int s = 0; s < 2; ++s) {
            short8 af[2], bfr[2];
#pragma unroll
            for (int im = 0; im < 2; im++) {
                int R = wr * 32 + im * 16 + lrow;
                af[im] = *(const short8*)&As[R * 64 + (((s * 4 + quad) ^ (R & 7)) * 8)];
            }
#pragma unroll
            for (int in = 0; in < 2; in++) {
                int R = wc * 32 + in * 16 + lrow;
                bfr[in] = *(const short8*)&Bs[R * 64 + (((s * 4 + quad) ^ (R & 7)) * 8)];
            }
#pragma unroll
            for (int im = 0; im < 2; im++)
#pragma unroll
                for (int in = 0; in < 2; in++)
                    acc[im][in] = __builtin_amdgcn_mfma_f32_16x16x32_bf16(af[im], bfr[in], acc[im][in], 0, 0, 0);
        }
    }

#pragma unroll
    for (int im = 0; im < 2; im++)
#pragma unroll
        for (int in = 0; in < 2; in++) {
            int gi0 = bm * 64 + wr * 32 + im * 16 + quad * 4;
            int gj = bn * 64 + wc * 32 + in * 16 + lrow;
            float bias = (gj < 512) ? bq[gj] : (gj < 1024 ? bk[gj - 512] : bv[gj - 1024]);
            u16x4 pack;
#pragma unroll
            for (int r = 0; r < 4; r++) {
                u16 hv = f2bf(acc[im][in][r] + bias);
                C[(size_t)(gi0 + r) * 1536 + gj] = hv;
                pack[r] = hv;
            }
            if (gj >= 1024) {   // vT[b][d][s], 4 consecutive s -> 8B store
                int bb = gi0 >> 11, s = gi0 & 2047;
                *(u16x4*)&vT[((size_t)bb * DIM + (gj - 1024)) * SEQ + s] = pack;
            }
        }
}

// =====================================================================
// 64x64-tile bf16 GEMM, BK=64 (16 KB LDS), gl_lds staging, mask-7 swizzle.
// MODE 1: scores -> attnH bf16, dist+exp epilogue + lsum atomics; causal skip
// MODE 2: PV (non-split) -> out fp32 plain store with 1/lsum; bm reversed
// =====================================================================
template<int MODE>
__global__ __launch_bounds__(256, 8) void gemm64_kernel(
    const u16* __restrict__ A, int lda, long long sA,
    const u16* __restrict__ Bt, int ldb, long long sB,
    void* __restrict__ Cv, int ldc, long long sC,
    float* __restrict__ lsum,
    const float* __restrict__ qn2v, const float* __restrict__ kn2v,
    const float* __restrict__ curvp, const float* __restrict__ tempp)
{
    int bn = blockIdx.x, b = blockIdx.z;
    int bm = (MODE == 2) ? (gridDim.y - 1 - blockIdx.y) : blockIdx.y;
    if (MODE == 1 && bn > bm) return;   // causal tile skip

    __shared__ __align__(16) u16 As[64 * 64];
    __shared__ __align__(16) u16 Bs[64 * 64];

    int t = threadIdx.x, wave = t >> 6, lane = t & 63;
    int wr = wave >> 1, wc = wave & 1;
    int lrow = lane & 15, quad = lane >> 4;
    int srow = lane >> 3, sc = lane & 7;

    const u16* Ab = A + (size_t)b * sA + (size_t)(bm * 64) * lda;
    const u16* Bb = Bt + (size_t)b * sB + (size_t)(bn * 64) * ldb;

    float4e acc[2][2];
#pragma unroll
    for (int i = 0; i < 2; i++)
#pragma unroll
        for (int j = 0; j < 2; j++) acc[i][j] = (float4e){0.f, 0.f, 0.f, 0.f};

    int kIters = (MODE == 2) ? (bm + 1) : 8;

    for (int kt = 0; kt < kIters; ++kt) {
        int k0 = kt << 6;
        __syncthreads();
#pragma unroll
        for (int h = 0; h < 2; ++h) {
            int q = wave * 2 + h;
            int row = q * 8 + srow;
            int c = sc ^ srow;
            gl_lds16(Ab + (size_t)row * lda + k0 + c * 8, &As[q * 512]);
            gl_lds16(Bb + (size_t)row * ldb + k0 + c * 8, &Bs[q * 512]);
        }
        __syncthreads();
#pragma unroll
        for (int s = 0; s < 2; ++s) {
            short8 af[2], bfr[2];
#pragma unroll
            for (int im = 0; im < 2; im++) {
                int R = wr * 32 + im * 16 + lrow;
                af[im] = *(const short8*)&As[R * 64 + (((s * 4 + quad) ^ (R & 7)) * 8)];
            }
#pragma unroll
            for (int in = 0; in < 2; in++) {
                int R = wc * 32 + in * 16 + lrow;
                bfr[in] = *(const short8*)&Bs[R * 64 + (((s * 4 + quad) ^ (R & 7)) * 8)];
            }
#pragma unroll
            for (int im = 0; im < 2; im++)
#pragma unroll
                for (int in = 0; in < 2; in++)
                    acc[im][in] = __builtin_amdgcn_mfma_f32_16x16x32_bf16(af[im], bfr[in], acc[im][in], 0, 0, 0);
        }
    }

    if (MODE == 1) {
        float kv = curv_of(curvp[0]);
        float absk = fabsf(kv);
        float sk = sqrtf(fmaxf(absk, 1e-5f));
        float invsk = 1.0f / sk;
        float invT = 1.0f / (tempp[0] + 1e-8f);
        u16* Cb = (u16*)Cv + (size_t)b * sC;

        float psum[2][4];
#pragma unroll
        for (int im = 0; im < 2; im++)
#pragma unroll
            for (int r = 0; r < 4; r++) psum[im][r] = 0.f;

#pragma unroll
        for (int im = 0; im < 2; im++) {
#pragma unroll
            for (int r = 0; r < 4; r++) {
                int gi = bm * 64 + wr * 32 + im * 16 + quad * 4 + r;
                float qn = qn2v[b * SEQ + gi];
#pragma unroll
                for (int in = 0; in < 2; in++) {
                    int gj = bn * 64 + wc * 32 + in * 16 + lrow;
                    float kn = kn2v[b * SEQ + gj];
                    float dot = acc[im][in][r];
                    float diff2 = fmaxf(qn + kn - 2.f * dot, 0.f);
                    float dist;
                    if (absk < 0.01f) {
                        dist = sqrtf(diff2 + 1e-12f);
                    } else if (kv < 0.f) {
                        float denom = fmaxf((1.f - absk * qn) * (1.f - absk * kn), 1e-5f);
                        float arg = fmaxf(1.f + 2.f * absk * diff2 / denom, 1.f + 1e-7f);
                        dist = acoshf(arg) * invsk;
                    } else {
                        float c = fminf(fmaxf(absk * dot, -1.f + 1e-7f), 1.f - 1e-7f);
                        dist = fast_acos(c) * invsk;
                    }
                    float s = -dist * invT;
                    float e = (gj <= gi) ? __expf(s) : 0.f;   // scores<=0 -> no max shift
                    Cb[(size_t)gi * ldc + gj] = f2bf(e);
                    psum[im][r] += e;
                }
            }
        }
#pragma unroll
        for (int im = 0; im < 2; im++)
#pragma unroll
            for (int r = 0; r < 4; r++) {
                float v = psum[im][r];
                v += __shfl_xor(v, 1);
                v += __shfl_xor(v, 2);
                v += __shfl_xor(v, 4);
                v += __shfl_xor(v, 8);
                if (lrow == 0) {
                    int gi = bm * 64 + wr * 32 + im * 16 + quad * 4 + r;
                    atomicAdd(&lsum[b * SEQ + gi], v);
                }
            }
    } else {
        float* Cb = (float*)Cv + (size_t)b * sC;
#pragma unroll
        for (int im = 0; im < 2; im++)
#pragma unroll
            for (int r = 0; r < 4; r++) {
                int gi = bm * 64 + wr * 32 + im * 16 + quad * 4 + r;
                float invl = 1.0f / lsum[b * SEQ + gi];
#pragma unroll
                for (int in = 0; in < 2; in++) {
                    int gd = bn * 64 + wc * 32 + in * 16 + lrow;
                    Cb[(size_t)gi * ldc + gd] = acc[im][in][r] * invl;
                }
            }
    }
}

// ---------------- projection: wave-per-row, 16B vector loads/stores; zeroes lsum ----------------
__global__ __launch_bounds__(256) void project_kernel(
    const u16* __restrict__ qkvh,
    u16* __restrict__ qm, u16* __restrict__ km,
    float* __restrict__ qn2, float* __restrict__ kn2,
    float* __restrict__ lsum,
    const float* __restrict__ curvp)
{
    if (threadIdx.x < 4) lsum[blockIdx.x * 4 + threadIdx.x] = 0.f;

    int wave = threadIdx.x >> 6, lane = threadIdx.x & 63;
    int r = blockIdx.x * 4 + wave;
    float kv = curv_of(curvp[0]);
    float absk = fabsf(kv);
    float sk = sqrtf(fmaxf(absk, 1e-5f));

    const u16* qrow = qkvh + (size_t)r * 1536;
    ushort8 qh = *(const ushort8*)&qrow[lane * 8];
    ushort8 kh = *(const ushort8*)&qrow[512 + lane * 8];

    float qv[8], kw[8];
    float sq = 0.f, s2 = 0.f;
#pragma unroll
    for (int e = 0; e < 8; e++) {
        qv[e] = bf2f(qh[e]); sq += qv[e] * qv[e];
        kw[e] = bf2f(kh[e]); s2 += kw[e] * kw[e];
    }
#pragma unroll
    for (int off = 1; off < 64; off <<= 1) {
        sq += __shfl_xor(sq, off);
        s2 += __shfl_xor(s2, off);
    }

    float sclq, sclk;
    {
        float nq = sqrtf(sq + 1e-12f);
        float nk = sqrtf(s2 + 1e-12f);
        if (absk < 0.01f) { sclq = 1.f; sclk = 1.f; }
        else if (kv < 0.f) {
            float mx = (1.0f - 1e-3f) / sk;
            sclq = fminf(1.f, mx / nq);
            sclk = fminf(1.f, mx / nk);
        } else {
            sclq = 1.f / (nq * sk);
            sclk = 1.f / (nk * sk);
        }
    }
    if (lane == 0) {
        qn2[r] = sq * sclq * sclq;
        kn2[r] = s2 * sclk * sclk;
    }
    ushort8 qo, ko;
#pragma unroll
    for (int e = 0; e < 8; e++) {
        qo[e] = f2bf(qv[e] * sclq);
        ko[e] = f2bf(kw[e] * sclk);
    }
    *(ushort8*)&qm[(size_t)r * 512 + lane * 8] = qo;
    *(ushort8*)&km[(size_t)r * 512 + lane * 8] = ko;
}

// ---------------- normalize: attnH bf16 -> attnF fp32 (zero upper-tri) ----------------
__global__ __launch_bounds__(256) void norm_attn_kernel(
    const u16* __restrict__ attnH, const float* __restrict__ lsum,
    float* __restrict__ attnF)
{
    int i = blockIdx.x, b = blockIdx.y, t = threadIdx.x;
    float inv = 1.0f / lsum[b * SEQ + i];
    const u16* rowh = attnH + ((size_t)b * SEQ + i) * SEQ;
    float* row = attnF + ((size_t)b * SEQ + i) * SEQ;
    int L = i + 1;
    int j0 = t * 8;
    float4 lo, hi;
    if (j0 + 8 <= L) {
        ushort8 h = *(const ushort8*)&rowh[j0];
        lo.x = bf2f(h[0]) * inv; lo.y = bf2f(h[1]) * inv;
        lo.z = bf2f(h[2]) * inv; lo.w = bf2f(h[3]) * inv;
        hi.x = bf2f(h[4]) * inv; hi.y = bf2f(h[5]) * inv;
        hi.z = bf2f(h[6]) * inv; hi.w = bf2f(h[7]) * inv;
    } else {
        float v[8];
#pragma unroll
        for (int e = 0; e < 8; e++)
            v[e] = (j0 + e < L) ? bf2f(rowh[j0 + e]) * inv : 0.f;
        lo = (float4){v[0], v[1], v[2], v[3]};
        hi = (float4){v[4], v[5], v[6], v[7]};
    }
    *(float4*)&row[j0] = lo;
    *(float4*)&row[j0 + 4] = hi;
}

// ---------------- launch ----------------
extern "C" void kernel_launch(void* const* d_in, const int* in_sizes, int n_in,
                              void* d_out, int out_size, void* d_ws, size_t ws_size,
                              hipStream_t stream) {
    (void)in_sizes; (void)n_in; (void)out_size; (void)ws_size;

    const float* x    = (const float*)d_in[0];
    const float* Wq   = (const float*)d_in[1];
    const float* bq   = (const float*)d_in[2];
    const float* Wk   = (const float*)d_in[3];
    const float* bk   = (const float*)d_in[4];
    const float* Wv   = (const float*)d_in[5];
    const float* bv   = (const float*)d_in[6];
    const float* curv = (const float*)d_in[7];
    const float* temp = (const float*)d_in[8];

    float* out   = (float*)d_out;                       // [4][2048][512]
    float* attnF = out + (size_t)NB * SEQ * DIM;        // [4][2048][2048]

    char* ws = (char*)d_ws;
    // layout (bytes):
    //   0         qkvh   25,165,824   (dead after project; aliased by attnH)
    //   33554432  qm      8,388,608
    //   41943040  km      8,388,608
    //   50331648  vT      8,388,608   (written by QKV epilogue)
    //   58720256  qn2        32,768
    //   58753024  kn2        32,768
    //   58785792  lsum       32,768
    // attnH (33,554,432) occupies [0, 33554432) — qkvh dead by scores time.
    u16*   qkvh  = (u16*)(ws + 0);
    u16*   qm    = (u16*)(ws + 33554432);
    u16*   km    = (u16*)(ws + 41943040);
    u16*   vT    = (u16*)(ws + 50331648);
    float* qn2   = (float*)(ws + 58720256);
    float* kn2   = (float*)(ws + 58753024);
    float* lsum  = (float*)(ws + 58785792);
    u16*   attnH = (u16*)(ws + 0);

    // K1: QKV GEMM (M=8192, N=1536, K=512), fp32 inputs staged inline, +bias, fused vT
    qkv_kernel<<<dim3(1536 / 64, 8192 / 64, 1), 256, 0, stream>>>(
        x, Wq, Wk, Wv, bq, bk, bv, qkvh, vT);

    // K2: projection (+ lsum zero)
    project_kernel<<<NB * SEQ / 4, 256, 0, stream>>>(qkvh, qm, km, qn2, kn2, lsum, curv);

    // K3: scores + dist + exp (unnormalized bf16) + row sums
    gemm64_kernel<1><<<dim3(SEQ / 64, SEQ / 64, NB), 256, 0, stream>>>(
        qm, 512, (long long)SEQ * DIM, km, 512, (long long)SEQ * DIM,
        (void*)attnH, SEQ, (long long)SEQ * SEQ,
        lsum, qn2, kn2, curv, temp);

    // K4: PV (non-split, longest blocks first), plain store with 1/l scaling
    gemm64_kernel<2><<<dim3(DIM / 64, SEQ / 64, NB), 256, 0, stream>>>(
        attnH, SEQ, (long long)SEQ * SEQ, vT, SEQ, (long long)DIM * SEQ,
        (void*)out, DIM, (long long)SEQ * DIM,
        lsum, nullptr, nullptr, nullptr, nullptr);

    // K5: attention fp32 output from bf16 + 1/l
    norm_attn_kernel<<<dim3(SEQ, NB), 256, 0, stream>>>(attnH, lsum, attnF);
}